// Round 1
// baseline (239.060 us; speedup 1.0000x reference)
//
#include <hip/hip_runtime.h>

// Embedding gather: out[t*768 + e] = weight[e*VOCAB + x[t]]
// x: [8,2048] int32 (d_in[0]); weight: [768, 50257] f32 (d_in[1])
// out: [8,2048,768] f32

#define VOCAB 50257
#define EMBED 768
#define EMBED4 (EMBED / 4)   // 192 float4 per token

__global__ __launch_bounds__(256) void embed_gather_kernel(
    const int* __restrict__ x,
    const float* __restrict__ w,
    float4* __restrict__ out4,
    int total4) {
  int i = blockIdx.x * blockDim.x + threadIdx.x;
  int stride = gridDim.x * blockDim.x;
  for (; i < total4; i += stride) {
    int t  = i / EMBED4;          // token position
    int e4 = i - t * EMBED4;      // which float4 within the embedding
    int v  = x[t];                // vocab index (broadcast across 192 lanes)
    const float* base = w + (size_t)(e4 * 4) * VOCAB + (size_t)v;
    float4 r;
    r.x = base[0];
    r.y = base[(size_t)VOCAB];
    r.z = base[(size_t)2 * VOCAB];
    r.w = base[(size_t)3 * VOCAB];
    out4[i] = r;
  }
}

extern "C" void kernel_launch(void* const* d_in, const int* in_sizes, int n_in,
                              void* d_out, int out_size, void* d_ws, size_t ws_size,
                              hipStream_t stream) {
  const int*   x = (const int*)d_in[0];     // 8*2048 indices
  const float* w = (const float*)d_in[1];   // 768*50257 weights
  float4* out4 = (float4*)d_out;

  const int n_tok  = in_sizes[0];           // 16384
  const int total4 = n_tok * EMBED4;        // 3,145,728

  const int block = 256;
  int grid = (total4 + block - 1) / block;  // 12288 — exact cover, one elem/thread
  embed_gather_kernel<<<grid, block, 0, stream>>>(x, w, out4, total4);
}

// Round 2
// 74.105 us; speedup vs baseline: 3.2259x; 3.2259x over previous
//
#include <hip/hip_runtime.h>

// out[t*768 + e] = weight[e*VOCAB + x[t]]
// Strategy: counting-sort tokens into 32-column windows (one cache line per
// weight row per window), then per (window, row-group) workgroup: stage the
// 192x32 weight slab into LDS (coalesced float4, each HBM line fetched exactly
// once) and serve the bucket's tokens from LDS with coalesced output stores.

#define VOCAB 50257
#define EMBED 768
#define WINB 32
#define NWIN 1571          // ceil(VOCAB/32)
#define NWIN_P 2048        // padded for scan
#define RG 4               // row groups
#define ROWS 192           // EMBED / RG
#define LSTRIDE 33         // +1 pad -> token-phase reads bank-conflict-free

__global__ __launch_bounds__(256) void zero_kernel(int* __restrict__ p, int n) {
  int i = blockIdx.x * blockDim.x + threadIdx.x;
  if (i < n) p[i] = 0;
}

__global__ __launch_bounds__(256) void hist_kernel(const int* __restrict__ x,
                                                   int* __restrict__ cnt, int n) {
  int i = blockIdx.x * blockDim.x + threadIdx.x;
  if (i < n) atomicAdd(&cnt[x[i] >> 5], 1);
}

__global__ __launch_bounds__(1024) void scan_kernel(const int* __restrict__ cnt,
                                                    int* __restrict__ off,
                                                    int* __restrict__ cur) {
  __shared__ int a[NWIN_P], b[NWIN_P];
  int t = threadIdx.x;
  a[t] = cnt[t];
  a[t + 1024] = cnt[t + 1024];
  __syncthreads();
  int* src = a;
  int* dst = b;
  for (int d = 1; d < NWIN_P; d <<= 1) {
    for (int i = t; i < NWIN_P; i += 1024)
      dst[i] = (i >= d) ? src[i] + src[i - d] : src[i];
    __syncthreads();
    int* tmp = src; src = dst; dst = tmp;
  }
  for (int i = t; i < NWIN_P; i += 1024) {
    int e = (i > 0) ? src[i - 1] : 0;  // exclusive prefix
    off[i] = e;
    cur[i] = e;
  }
}

__global__ __launch_bounds__(256) void scatter_kernel(const int* __restrict__ x,
                                                      int* __restrict__ cur,
                                                      int* __restrict__ sorted,
                                                      int n) {
  int i = blockIdx.x * blockDim.x + threadIdx.x;
  if (i < n) {
    int v = x[i];
    int p = atomicAdd(&cur[v >> 5], 1);
    sorted[p] = (i << 5) | (v & 31);   // pack token id + in-window column
  }
}

__global__ __launch_bounds__(256) void gather_kernel(const float* __restrict__ w,
                                                     const int* __restrict__ off,
                                                     const int* __restrict__ sorted,
                                                     float* __restrict__ out) {
  __shared__ float lds[ROWS * LSTRIDE];
  const int wid = blockIdx.x % NWIN;   // column window
  const int rg  = blockIdx.x / NWIN;   // row group
  const int row0 = rg * ROWS;
  const int col0 = wid * WINB;
  const int tid = threadIdx.x;

  // --- stage ROWS x 32 slab, coalesced (8 float4 per row = one 128B line x4) ---
  if (wid != NWIN - 1) {
    #pragma unroll
    for (int j = tid; j < ROWS * 8; j += 256) {
      int r = j >> 3, c4 = (j & 7) << 2;
      float4 v = *(const float4*)&w[(size_t)(row0 + r) * VOCAB + col0 + c4];
      float* d = &lds[r * LSTRIDE + c4];
      d[0] = v.x; d[1] = v.y; d[2] = v.z; d[3] = v.w;
    }
  } else {
    // last window: only 17 valid columns, guarded scalar loads
    for (int j = tid; j < ROWS * 8; j += 256) {
      int r = j >> 3, c4 = (j & 7) << 2;
      float* d = &lds[r * LSTRIDE + c4];
      for (int u = 0; u < 4; ++u) {
        int c = col0 + c4 + u;
        d[u] = (c < VOCAB) ? w[(size_t)(row0 + r) * VOCAB + c] : 0.f;
      }
    }
  }
  __syncthreads();

  // --- serve bucket tokens from LDS ---
  const int beg = off[wid], end = off[wid + 1];
  const int wave = tid >> 6, lane = tid & 63;
  for (int i = beg + wave; i < end; i += 4) {
    int pk = sorted[i];           // broadcast load
    int t = pk >> 5, c = pk & 31;
    float* o = &out[(size_t)t * EMBED + row0];
    #pragma unroll
    for (int k = 0; k < 3; ++k)   // bank = (lane + c) % 32 -> 2-way, free
      o[k * 64 + lane] = lds[(k * 64 + lane) * LSTRIDE + c];
  }
}

extern "C" void kernel_launch(void* const* d_in, const int* in_sizes, int n_in,
                              void* d_out, int out_size, void* d_ws, size_t ws_size,
                              hipStream_t stream) {
  const int*   x = (const int*)d_in[0];
  const float* w = (const float*)d_in[1];
  float* out = (float*)d_out;
  const int n = in_sizes[0];          // 16384 tokens

  int* cnt    = (int*)d_ws;           // [2048]
  int* off    = cnt + NWIN_P;         // [2048]
  int* cur    = off + NWIN_P;         // [2048]
  int* sorted = cur + NWIN_P;         // [n]

  zero_kernel<<<NWIN_P / 256, 256, 0, stream>>>(cnt, NWIN_P);
  hist_kernel<<<(n + 255) / 256, 256, 0, stream>>>(x, cnt, n);
  scan_kernel<<<1, 1024, 0, stream>>>(cnt, off, cur);
  scatter_kernel<<<(n + 255) / 256, 256, 0, stream>>>(x, cur, sorted, n);
  gather_kernel<<<NWIN * RG, 256, 0, stream>>>(w, off, sorted, out);
}

// Round 3
// 52.506 us; speedup vs baseline: 4.5530x; 1.4114x over previous
//
#include <hip/hip_runtime.h>

// out[t*768 + e] = weight[e*VOCAB + x[t]]
// Counting-sort tokens into 32-col windows, then per (window,row-group) block:
// stage 192x32 weight slab to LDS (each HBM line fetched once per XCD thanks
// to XCD-chunked swizzle), serve bucket tokens from LDS with coalesced stores.

#define VOCAB 50257
#define EMBED 768
#define WINB 32
#define NWIN 1571          // ceil(VOCAB/32)
#define NWIN_P 2048        // padded for scan
#define RG 4               // row groups
#define ROWS 192           // EMBED / RG
#define LSTRIDE 33         // +1 pad -> serve-phase reads are 2-way (free)
#define CHUNK 256          // token-list LDS chunk

// --- fused zero + histogram + exclusive scan (single block) ---
__global__ __launch_bounds__(1024) void hist_scan_kernel(const int* __restrict__ x,
                                                         int n,
                                                         int* __restrict__ off,
                                                         int* __restrict__ cur) {
  __shared__ int h[NWIN_P];
  __shared__ int b[NWIN_P];
  const int t = threadIdx.x;
  h[t] = 0; h[t + 1024] = 0;
  __syncthreads();
  for (int i = t; i < n; i += 1024) atomicAdd(&h[x[i] >> 5], 1);
  __syncthreads();
  int* src = h; int* dst = b;
  for (int d = 1; d < NWIN_P; d <<= 1) {
    for (int i = t; i < NWIN_P; i += 1024)
      dst[i] = (i >= d) ? src[i] + src[i - d] : src[i];
    __syncthreads();
    int* tmp = src; src = dst; dst = tmp;
  }
  for (int i = t; i < NWIN_P; i += 1024) {
    int e = (i > 0) ? src[i - 1] : 0;
    off[i] = e;
    cur[i] = e;
  }
}

__global__ __launch_bounds__(256) void scatter_kernel(const int* __restrict__ x,
                                                      int* __restrict__ cur,
                                                      int* __restrict__ sorted,
                                                      int n) {
  int i = blockIdx.x * blockDim.x + threadIdx.x;
  if (i < n) {
    int v = x[i];
    int p = atomicAdd(&cur[v >> 5], 1);
    sorted[p] = (i << 5) | (v & 31);
  }
}

__device__ __forceinline__ int xcd_swizzle(int bid, int nwg) {
  // bijective: hw blocks on XCD k get a contiguous logical chunk (m204)
  const int NX = 8;
  int q = nwg / NX, r = nwg % NX;
  int xcd = bid % NX, idx = bid / NX;
  int base = (xcd < r) ? xcd * (q + 1) : r * (q + 1) + (xcd - r) * q;
  return base + idx;
}

__global__ __launch_bounds__(256) void gather_kernel(const float* __restrict__ w,
                                                     const int* __restrict__ off,
                                                     const int* __restrict__ sorted,
                                                     float* __restrict__ out) {
  __shared__ float lds[ROWS * LSTRIDE];
  __shared__ int toks[CHUNK];
  const int logical = xcd_swizzle(blockIdx.x, NWIN * RG);
  const int wid = logical % NWIN;   // contiguous within an XCD chunk
  const int rg  = logical / NWIN;
  const int row0 = rg * ROWS;
  const int col0 = wid * WINB;
  const int tid = threadIdx.x;

  // bucket bounds (uniform scalar loads)
  int beg = off[wid], end = off[wid + 1];

  // --- stage ROWS x 32 slab, coalesced float4 (6 per thread) ---
  if (wid != NWIN - 1) {
    #pragma unroll
    for (int j = tid; j < ROWS * 8; j += 256) {
      int r = j >> 3, c4 = (j & 7) << 2;
      float4 v = *(const float4*)&w[(size_t)(row0 + r) * VOCAB + col0 + c4];
      float* d = &lds[r * LSTRIDE + c4];
      d[0] = v.x; d[1] = v.y; d[2] = v.z; d[3] = v.w;
    }
  } else {
    for (int j = tid; j < ROWS * 8; j += 256) {
      int r = j >> 3, c4 = (j & 7) << 2;
      float* d = &lds[r * LSTRIDE + c4];
      for (int u = 0; u < 4; ++u) {
        int c = col0 + c4 + u;
        d[u] = (c < VOCAB) ? w[(size_t)(row0 + r) * VOCAB + c] : 0.f;
      }
    }
  }

  // --- bulk-load first token chunk (overlaps stage loads) ---
  int m = end - beg; if (m > CHUNK) m = CHUNK;
  if (tid < m) toks[tid] = sorted[beg + tid];
  __syncthreads();

  const int wave = tid >> 6, lane = tid & 63;
  while (true) {
    for (int i = wave; i < m; i += 4) {
      int pk = toks[i];               // LDS broadcast
      int t = pk >> 5, c = pk & 31;
      float* o = &out[(size_t)t * EMBED + row0];
      #pragma unroll
      for (int k = 0; k < 3; ++k)     // bank=(lane+c)%32 -> 2-way, free
        o[k * 64 + lane] = lds[(k * 64 + lane) * LSTRIDE + c];
    }
    beg += m;
    if (beg >= end) break;
    __syncthreads();
    m = end - beg; if (m > CHUNK) m = CHUNK;
    if (tid < m) toks[tid] = sorted[beg + tid];
    __syncthreads();
  }
}

extern "C" void kernel_launch(void* const* d_in, const int* in_sizes, int n_in,
                              void* d_out, int out_size, void* d_ws, size_t ws_size,
                              hipStream_t stream) {
  const int*   x = (const int*)d_in[0];
  const float* w = (const float*)d_in[1];
  float* out = (float*)d_out;
  const int n = in_sizes[0];          // 16384 tokens

  int* off    = (int*)d_ws;           // [2049 used]
  int* cur    = off + NWIN_P + 1;     // [2048]
  int* sorted = cur + NWIN_P;         // [n]

  hist_scan_kernel<<<1, 1024, 0, stream>>>(x, n, off, cur);
  scatter_kernel<<<(n + 255) / 256, 256, 0, stream>>>(x, cur, sorted, n);
  gather_kernel<<<NWIN * RG, 256, 0, stream>>>(w, off, sorted, out);
}